// Round 15
// baseline (96.544 us; speedup 1.0000x reference)
//
#include <hip/hip_runtime.h>

// LabelizerNet: avg-pool(6,2) -> RGB->HSV -> yellow/blue mask -> per-panel max/min
// Input : states (N, 3, 84, 84) f32   (N = 4096)
// Output: labels (N, 6) f32  [yellow panels 0..2, blue panels 0..2]
//
// Round 15: zero-overfetch ring pipeline. Frames {24,20,20,20} rows; each input
// row fetched exactly once; quarter q computes from frame q + 4-row tail of
// frame q-1 (already in LDS). Ring of 3 buffers (b0 512 f4/ch holds f0 then f3;
// b1,b2 448 f4/ch), 1-ahead global_load_lds staging with per-wave counted vmcnt
// (waves issue 6|5 chunks -> vmcnt(6)|vmcnt(5)) + raw s_barrier, as in r14.
// Math bit-identical to all passing rounds.

#define CH_ELEMS 7056              // 84*84
#define CH_F4    1764              // 7056/4
#define IMG_F4   5292              // 3*7056/4
// LDS layout in float4 units:
#define B0 0                       // slot 512/ch (holds f0, then f3)
#define B1 1536                    // slot 448/ch
#define B2 2880                    // slot 448/ch
#define LDS_TOT 4224               // 67584 B

__device__ __forceinline__ void gl_lds16(const float4* g, float4* l) {
    __builtin_amdgcn_global_load_lds(
        (const __attribute__((address_space(1))) void*)(uintptr_t)(const void*)g,
        (__attribute__((address_space(3))) void*)(uintptr_t)(void*)l,
        16, 0, 0);
}

__global__ __launch_bounds__(256)
void labelizer_fused(const float* __restrict__ in, float* __restrict__ out) {
    __shared__ float4 s4[LDS_TOT];
    __shared__ unsigned bmask;

    const int tid = threadIdx.x;
    const int img = blockIdx.x;
    const int wid = tid >> 6, lane = tid & 63;
    if (tid == 0) bmask = 0u;

    const float4* base = (const float4*)in + (size_t)img * IMG_F4;
    unsigned my = 0u;

    // stage frame: fs_row=first input row, fl=f4 per channel, nc=chunks per
    // channel, bb/ss = LDS buffer base & per-channel slot. Chunk t -> wave t%4;
    // per-wave instruction count: 3*nc/4 rounded -> 6 (nc=8) or 6|5|5|5 (nc=7).
    auto stage = [&](int fs_row, int fl, int nc, int bb, int ss) {
        const int tot = 3 * nc;
        for (int t = wid; t < tot; t += 4) {
            int c = t / nc, k = t - c * nc;
            int i = k * 64 + lane;
            gl_lds16(base + c * CH_F4 + fs_row * 21 + min(i, fl - 1),
                     s4 + bb + c * ss + i);
        }
    };

    // compute one quarter. Row r (0..23) of channel c lives at:
    //   r < rsplit : bA + c*sA + (aA+r)*21   (tail of previous frame)
    //   r >= rsplit: bB + c*sB + (aB+r)*21   (current frame)
    auto compute = [&](int rsplit, int bA, int sA, int aA, int bB, int sB, int aB) {
        if (tid < 200) {
            const int pr = tid / 20;             // pooled row within quarter
            const int xp = tid - pr * 20;        // pair-column 0..19
            const int x0 = 2 * xp, x1 = 2 * xp + 1;

            float t0[3], t1[3];
            #pragma unroll
            for (int c = 0; c < 3; ++c) {
                float P0[3], P1[3];
                #pragma unroll
                for (int j = 0; j < 3; ++j) {
                    int r0 = 2 * pr + 2 * j;
                    int r1 = r0 + 1;
                    int o0 = (r0 < rsplit) ? (bA + c * sA + (aA + r0) * 21)
                                           : (bB + c * sB + (aB + r0) * 21);
                    int o1 = (r1 < rsplit) ? (bA + c * sA + (aA + r1) * 21)
                                           : (bB + c * sB + (aB + r1) * 21);
                    const float4* ra = &s4[o0 + xp];
                    const float4* rb = &s4[o1 + xp];
                    float4 qa0 = ra[0], qa1 = ra[1];
                    float4 qb0 = rb[0], qb1 = rb[1];
                    float a01 = qa0.x + qa0.y, a23 = qa0.z + qa0.w;
                    float a45 = qa1.x + qa1.y, a67 = qa1.z + qa1.w;
                    float rsa0 = (a01 + a23) + a45;      // rs[2j],  window x0
                    float rsa1 = (a23 + a45) + a67;      // rs[2j],  window x1
                    float b01 = qb0.x + qb0.y, b23 = qb0.z + qb0.w;
                    float b45 = qb1.x + qb1.y, b67 = qb1.z + qb1.w;
                    float rsb0 = (b01 + b23) + b45;      // rs[2j+1], window x0
                    float rsb1 = (b23 + b45) + b67;      // rs[2j+1], window x1
                    P0[j] = rsa0 + rsb0;                 // pair sum
                    P1[j] = rsa1 + rsb1;
                }
                t0[c] = (P0[0] + P0[1]) + P0[2];     // == ((rs0+rs1)+(rs2+rs3))+(rs4+rs5)
                t1[c] = (P1[0] + P1[1]) + P1[2];
            }

            #pragma unroll
            for (int e = 0; e < 2; ++e) {
                float r = ((e == 0) ? t0[0] : t1[0]) / 36.0f;
                float g = ((e == 0) ? t0[1] : t1[1]) / 36.0f;
                float bb2 = ((e == 0) ? t0[2] : t1[2]) / 36.0f;

                float maxc = fmaxf(r, fmaxf(g, bb2));
                float minc = fminf(r, fminf(g, bb2));
                float delta = maxc - minc;
                float s = (maxc == 0.0f) ? 0.0f : delta / maxc;
                float v = maxc;
                float h = 0.0f;
                if (delta != 0.0f) {
                    float rc = (maxc - r) / delta;
                    float gc = (maxc - g) / delta;
                    float bc = (maxc - bb2) / delta;
                    float hh = (r == maxc) ? (bc - gc)
                             : ((g == maxc) ? (2.0f + rc - bc)
                                            : (4.0f + gc - rc));
                    h = hh / 6.0f;           // in (-1/6, 5/6); floor-mod 1:
                    if (h < 0.0f) h += 1.0f;
                }
                bool satval = (s > 0.5f) && (v > 0.5f);
                int m = 0;
                if (satval && h >= 0.1f && h <= 0.2f) m = 1;
                else if (satval && h >= 0.55f && h <= 0.7f) m = -1;

                int x = (e == 0) ? x0 : x1;
                if (x < 39) {                 // col 39 excluded (40//3*3 == 39)
                    int pan = x / 13;         // 0..2
                    unsigned bit = (m > 0) ? 1u : (m < 0) ? 2u : 4u;
                    my |= bit << (3 * pan);
                }
            }
        }
    };

    // ---- pipeline: frames f0(rows 0-23), f1(24-43), f2(44-63), f3(64-83) ----
    stage(0, 504, 8, B0, 512);           // s0: 6 chunks/wave (uniform)

    // q=0: reads f0 only
    stage(24, 420, 7, B1, 448);          // s1: 6|5|5|5
    if (wid == 0) asm volatile("s_waitcnt vmcnt(6)" ::: "memory");
    else          asm volatile("s_waitcnt vmcnt(5)" ::: "memory");
    __builtin_amdgcn_s_barrier();
    compute(0, 0, 0, 0, B0, 512, 0);
    __builtin_amdgcn_s_barrier();

    // q=1: f0 tail (rows 20-23) + f1
    stage(44, 420, 7, B2, 448);          // s2
    if (wid == 0) asm volatile("s_waitcnt vmcnt(6)" ::: "memory");
    else          asm volatile("s_waitcnt vmcnt(5)" ::: "memory");
    __builtin_amdgcn_s_barrier();
    compute(4, B0, 512, 20, B1, 448, -4);
    __builtin_amdgcn_s_barrier();

    // q=2: f1 tail + f2
    stage(64, 420, 7, B0, 512);          // s3 (reuses b0; f0 last read in q=1)
    if (wid == 0) asm volatile("s_waitcnt vmcnt(6)" ::: "memory");
    else          asm volatile("s_waitcnt vmcnt(5)" ::: "memory");
    __builtin_amdgcn_s_barrier();
    compute(4, B1, 448, 16, B2, 448, -4);
    __builtin_amdgcn_s_barrier();

    // q=3: f2 tail + f3 (in b0)
    asm volatile("s_waitcnt vmcnt(0)" ::: "memory");
    __builtin_amdgcn_s_barrier();
    compute(4, B2, 448, 16, B0, 512, -4);

    // ---- in-block reduce -> direct output write ----
    #pragma unroll
    for (int off = 32; off > 0; off >>= 1) my |= __shfl_xor(my, off);
    if ((tid & 63) == 0 && my) atomicOr(&bmask, my);
    __syncthreads();

    if (tid < 6) {
        int pan = (tid < 3) ? tid : tid - 3;
        unsigned w = bmask >> (3 * pan);
        bool anyY = w & 1u;
        bool anyB = (w >> 1) & 1u;
        bool anyZ = (w >> 2) & 1u;
        float val;
        if (tid < 3) val = anyY ? 1.0f : (anyZ ? 0.0f : -1.0f);   // max(panel)
        else         val = anyB ? 1.0f : (anyZ ? 0.0f : -1.0f);   // -min(panel)
        out[(size_t)img * 6 + tid] = val;
    }
}

extern "C" void kernel_launch(void* const* d_in, const int* in_sizes, int n_in,
                              void* d_out, int out_size, void* d_ws, size_t ws_size,
                              hipStream_t stream) {
    const float* states = (const float*)d_in[0];
    float* out = (float*)d_out;
    int N = in_sizes[0] / (3 * CH_ELEMS);   // 4096
    labelizer_fused<<<N, 256, 0, stream>>>(states, out);
}